// Round 13
// baseline (88.342 us; speedup 1.0000x reference)
//
#include <hip/hip_runtime.h>

#define IMH 512
#define IMW 512
#define BATCH 8
#define NTOK 20480
#define NC 4096
#define NF 16384
#define ED 128

// ---------------- Kernel 1: coarse (blocks 0-1023) + edge (1024-1535) ------
// Edge blocks count completion per batch; the LAST tile-block of each batch
// inline-runs the 256-thread ballot scan (deterministic result regardless of
// which block executes it).
__global__ __launch_bounds__(256) void k1_all(const float* __restrict__ x,
                                              const float* __restrict__ wc,
                                              const float* __restrict__ bc,
                                              const float* __restrict__ temb,
                                              float* __restrict__ out,
                                              double* __restrict__ edges,
                                              double* __restrict__ tsum,
                                              unsigned long long* __restrict__ halfbits,
                                              int* __restrict__ halfbase,
                                              int* __restrict__ Kout,
                                              int* __restrict__ done,
                                              float* __restrict__ mask_out) {
    __shared__ float esm[66][68];
    __shared__ double dred[4];
    __shared__ unsigned long long hb_s[256];
    __shared__ int wtot[4];
    __shared__ int flag_s;
    int blk = blockIdx.x;
    int t = threadIdx.x;
    int lane = t & 63, wid = t >> 6;
    if (blk < 1024) {
        // ---- coarse role: 32 patches/block, wave-uniform scalar loads ----
        int b = blk >> 7;
        int pblk = (blk & 127) * 32;
        int wv = __builtin_amdgcn_readfirstlane(t >> 6);
        int h = wv & 1;
        int p0 = pblk + (wv >> 1) * 16;
        int d = h * 64 + lane;
        float wcol[64];
        #pragma unroll
        for (int k = 0; k < 64; ++k) wcol[k] = wc[k * ED + d];
        float base = bc[d] + temb[d];
        const float* img = x + ((size_t)b * IMH + (p0 >> 6) * 8) * IMW + (p0 & 63) * 8;
        float* dst = out + ((size_t)b * NTOK + p0) * ED + d;
        #pragma unroll
        for (int p = 0; p < 16; ++p) {
            const float* pimg = img + p * 8;    // wave-uniform -> scalar loads
            float acc = base;
            #pragma unroll
            for (int r = 0; r < 8; ++r) {
                const float* rp = pimg + r * IMW;
                acc += rp[0] * wcol[r * 8 + 0] + rp[1] * wcol[r * 8 + 1]
                     + rp[2] * wcol[r * 8 + 2] + rp[3] * wcol[r * 8 + 3]
                     + rp[4] * wcol[r * 8 + 4] + rp[5] * wcol[r * 8 + 5]
                     + rp[6] * wcol[r * 8 + 6] + rp[7] * wcol[r * 8 + 7];
            }
            dst[(size_t)p * ED] = acc;
        }
        return;
    }
    // ---- edge role: one 64x64 tile -> 16x16 fp64 cells + fp64 tile sum ----
    int blk2 = blk - 1024;
    int b = blk2 >> 6;
    int tile = blk2 & 63;
    int ty0 = (tile >> 3) * 64;
    int tx0 = (tile & 7) * 64;
    {
        const float* img = x + (size_t)b * (IMH * IMW);
        for (int idx = t; idx < 66 * 66; idx += 256) {
            int r = idx / 66, c = idx - r * 66;
            int gy = ty0 - 1 + r, gx = tx0 - 1 + c;
            float v = 0.f;
            if (gy >= 0 && gy < IMH && gx >= 0 && gx < IMW) v = img[gy * IMW + gx];
            esm[r][c] = v;
        }
    }
    __syncthreads();
    {
        int cy = t >> 4, cx = t & 15;
        double acc = 0.0;
        #pragma unroll
        for (int dy = 0; dy < 4; ++dy) {
            int py = cy * 4 + dy + 1;
            #pragma unroll
            for (int dx = 0; dx < 4; ++dx) {
                int px = cx * 4 + dx + 1;
                double a00 = (double)esm[py - 1][px - 1];
                double a01 = (double)esm[py - 1][px];
                double a02 = (double)esm[py - 1][px + 1];
                double a10 = (double)esm[py][px - 1];
                double a12 = (double)esm[py][px + 1];
                double a20 = (double)esm[py + 1][px - 1];
                double a21 = (double)esm[py + 1][px];
                double a22 = (double)esm[py + 1][px + 1];
                double sx = (a02 + 2.0 * a12 + a22) - (a00 + 2.0 * a10 + a20);
                double sy = (a20 + 2.0 * a21 + a22) - (a00 + 2.0 * a01 + a02);
                acc += sqrt(sx * sx + sy * sy);
            }
        }
        double cell = acc * (1.0 / 16.0);
        int gy = (ty0 >> 2) + cy;
        int gx = (tx0 >> 2) + cx;
        edges[((size_t)b << 14) + gy * 128 + gx] = cell;
        double sc = cell;
        #pragma unroll
        for (int off = 32; off > 0; off >>= 1) sc += __shfl_xor(sc, off);
        if (lane == 0) dred[wid] = sc;
    }
    __syncthreads();
    if (t == 0) {
        tsum[b * 64 + tile] = dred[0] + dred[1] + dred[2] + dred[3];
        __threadfence();                       // publish edges+tsum device-wide
        int old = atomicAdd(done + b, 1);      // device-scope
        flag_s = (old == 63) ? 1 : 0;
    }
    __syncthreads();
    if (flag_s == 0) return;
    // ---- last tile-block of batch b: inline ballot scan (256 threads) -----
    __threadfence();                           // acquire others' edges/tsum
    const double* ts = tsum + b * 64;
    double total = 0.0;
    #pragma unroll
    for (int j = 0; j < 64; ++j) total += ts[j];   // fixed order: bit-identical
    double mean = total * (1.0 / 16384.0);
    const double* e = edges + ((size_t)b << 14);
    float* mb = mask_out + ((size_t)b << 14);
    #pragma unroll 8
    for (int j = 0; j < 64; ++j) {
        double v = e[j * 256 + t];                 // coalesced
        bool sel = v > mean;
        unsigned long long bal = __ballot(sel);
        if (lane == 0) hb_s[j * 4 + wid] = bal;
        mb[j * 256 + t] = sel ? 1.0f : 0.0f;
    }
    __syncthreads();
    unsigned long long myb = hb_s[t];
    int cnt = __popcll(myb);
    int incl = cnt;
    #pragma unroll
    for (int off = 1; off < 64; off <<= 1) {
        int up = __shfl_up(incl, off);
        if (lane >= off) incl += up;
    }
    if (lane == 63) wtot[wid] = incl;
    __syncthreads();
    int woff = 0;
    #pragma unroll
    for (int w = 0; w < 4; ++w) { if (w < wid) woff += wtot[w]; }
    int excl = woff + incl - cnt;
    halfbits[b * 256 + t] = myb;
    halfbase[b * 256 + t] = excl;
    if (t == 255) Kout[b] = excl + cnt;
}

// ---------------- Kernel 2: fine embed, prelude-free, regular stores -------
// grid (256, 8): 64 patches (one half-row) per block, 256 threads.
__global__ __launch_bounds__(256) void k_fine(const float* __restrict__ x,
                                              const float* __restrict__ wfp,
                                              const float* __restrict__ bfp,
                                              const float* __restrict__ temb,
                                              const unsigned long long* __restrict__ halfbits,
                                              const int* __restrict__ halfbase,
                                              const int* __restrict__ Kout,
                                              float* __restrict__ out) {
    int b = blockIdx.y;
    int bx = blockIdx.x;                 // half-row index 0..255
    int t = threadIdx.x;
    __shared__ float smx[4][256];

    unsigned long long bits = halfbits[b * 256 + bx];
    int base = halfbase[b * 256 + bx];
    int K = Kout[b];

    int irow = (bx >> 1) * 4;            // image pixel row
    int icol = (bx & 1) * 256;           // image pixel col offset
    const float* img = x + ((size_t)b * IMH + irow) * IMW + icol;
    {
        int r = t >> 6, c4 = t & 63;     // 4 rows x 64 float4
        *(float4*)&smx[r][c4 * 4] = *(const float4*)&img[r * IMW + c4 * 4];
    }
    __syncthreads();

    int d4 = t & 31;
    int g = t >> 5;
    float4 wcol[16];
    #pragma unroll
    for (int k = 0; k < 16; ++k) wcol[k] = *(const float4*)&wfp[k * ED + d4 * 4];
    float4 fill = *(const float4*)&temb[ED + d4 * 4];
    float4 bse = *(const float4*)&bfp[d4 * 4];
    float4 fbase = make_float4(bse.x + fill.x, bse.y + fill.y, bse.z + fill.z, bse.w + fill.w);
    float* tok = out + ((size_t)b * NTOK + NC) * ED;
    int i0 = bx * 64;
    #pragma unroll
    for (int pp = 0; pp < 8; ++pp) {
        int p = g + pp * 8;              // 0..63 within half-row
        int i = i0 + p;
        if ((bits >> p) & 1ULL) {
            int below = __popcll(bits & ((1ULL << p) - 1ULL));
            int ps = base + below;
            float4 acc = fbase;
            #pragma unroll
            for (int r = 0; r < 4; ++r) {
                float4 vv = *(const float4*)&smx[r][p * 4];
                acc.x += vv.x * wcol[4 * r].x + vv.y * wcol[4 * r + 1].x + vv.z * wcol[4 * r + 2].x + vv.w * wcol[4 * r + 3].x;
                acc.y += vv.x * wcol[4 * r].y + vv.y * wcol[4 * r + 1].y + vv.z * wcol[4 * r + 2].y + vv.w * wcol[4 * r + 3].y;
                acc.z += vv.x * wcol[4 * r].z + vv.y * wcol[4 * r + 1].z + vv.z * wcol[4 * r + 2].z + vv.w * wcol[4 * r + 3].z;
                acc.w += vv.x * wcol[4 * r].w + vv.y * wcol[4 * r + 1].w + vv.z * wcol[4 * r + 2].w + vv.w * wcol[4 * r + 3].w;
            }
            *(float4*)(tok + ((size_t)ps * 32 + d4) * 4) = acc;
        }
        if (i >= K) {
            *(float4*)(tok + ((size_t)i * 32 + d4) * 4) = fill;
        }
    }
}

extern "C" void kernel_launch(void* const* d_in, const int* in_sizes, int n_in,
                              void* d_out, int out_size, void* d_ws, size_t ws_size,
                              hipStream_t stream) {
    const float* x    = (const float*)d_in[0];
    const float* wc   = (const float*)d_in[1];
    const float* bc   = (const float*)d_in[2];
    const float* wfp  = (const float*)d_in[3];
    const float* bfp  = (const float*)d_in[4];
    const float* temb = (const float*)d_in[5];
    float* out = (float*)d_out;

    char* wsb = (char*)d_ws;
    size_t off = 0;
    double* edges = (double*)(wsb + off);            off += (size_t)BATCH * NF * 8;   // 1 MiB
    double* tsum  = (double*)(wsb + off);            off += 4096;
    unsigned long long* halfbits = (unsigned long long*)(wsb + off); off += (size_t)BATCH * 256 * 8;
    int* halfbase = (int*)(wsb + off);               off += (size_t)BATCH * 256 * 4;
    int* Kout     = (int*)(wsb + off);               off += 64;
    int* done     = (int*)(wsb + off);               off += 64;
    float* mask_out = out + (size_t)BATCH * NTOK * ED;

    hipMemsetAsync(done, 0, BATCH * sizeof(int), stream);
    k1_all<<<dim3(1536), 256, 0, stream>>>(x, wc, bc, temb, out, edges, tsum,
                                           halfbits, halfbase, Kout, done, mask_out);
    k_fine<<<dim3(256, BATCH), 256, 0, stream>>>(x, wfp, bfp, temb,
                                                 halfbits, halfbase, Kout, out);
}